// Round 13
// baseline (3135.176 us; speedup 1.0000x reference)
//
#include <hip/hip_runtime.h>
#include <hip/hip_bf16.h>
#include <cstdint>
#include <cstddef>

typedef __bf16 bf16_t;
typedef __bf16 bf16x8 __attribute__((ext_vector_type(8)));
typedef float  f32x4  __attribute__((ext_vector_type(4)));

#define NB 64      // batch
#define NS 512     // source sequence length
#define NTD 128    // decoder steps
#define NE 256     // embedding dim
#define NH 512     // hidden dim
#define NG 2048    // 4*H (gates)
#define NW 256     // attention width

// one timestep of h in fragment layout = [4 bg][16 ks][64 lanes][4 dwords]
#define HSTEP_DW 16384u

__device__ __forceinline__ float sigm_f(float x) { return 1.f / (1.f + __expf(-x)); }
__device__ __forceinline__ float tanh_f(float x) {
  float e = __expf(2.f * x);
  return 1.f - 2.f / (e + 1.f);
}
__device__ __forceinline__ float bits2f(uint32_t b16) {
  uint32_t u = b16 << 16;
  return __builtin_bit_cast(float, u);
}
__device__ __forceinline__ uint32_t packh(float a, float b) {
  uint16_t lo = __builtin_bit_cast(uint16_t, (bf16_t)a);
  uint16_t hi = __builtin_bit_cast(uint16_t, (bf16_t)b);
  return (uint32_t)lo | ((uint32_t)hi << 16);
}
__device__ __forceinline__ uint32_t aload(const uint32_t* p) {
  return __hip_atomic_load(p, __ATOMIC_RELAXED, __HIP_MEMORY_SCOPE_AGENT);
}
__device__ __forceinline__ uint64_t aload64(const uint64_t* p) {
  return __hip_atomic_load(p, __ATOMIC_RELAXED, __HIP_MEMORY_SCOPE_AGENT);
}
__device__ __forceinline__ void astore(uint32_t* p, uint32_t v) {
  __hip_atomic_store(p, v, __ATOMIC_RELAXED, __HIP_MEMORY_SCOPE_AGENT);
}
// pick fp32 from packed 4x bf16 (uint2), r in [0,4)
__device__ __forceinline__ float xpick(uint2 v, int r) {
  uint32_t d = (r < 2) ? v.x : v.y;
  return bits2f((r & 1) ? (d >> 16) : (d & 0xffffu));
}

// ------- merged weight packing: all 5 matrices in one launch --------------
// B-fragment order: dst[((ntile*(K/32)+kstep)*64 + lane)*8 + j]
__global__ __launch_bounds__(256) void pack_all(
    const float* __restrict__ s0, bf16_t* __restrict__ d0,   // enc_Wih 2048x256
    const float* __restrict__ s1, bf16_t* __restrict__ d1,   // enc_Whh 2048x512
    const float* __restrict__ s2, bf16_t* __restrict__ d2,   // dec_Whh 2048x512
    const float* __restrict__ s3, bf16_t* __restrict__ d3,   // W1 256x512
    const float* __restrict__ s4, bf16_t* __restrict__ d4) { // W2 256x512
  int blk = blockIdx.x;
  const float* src; bf16_t* dst; int K, idx;
  if (blk < 2048)       { src = s0; dst = d0; K = 256; idx = blk * 256 + threadIdx.x; }
  else if (blk < 6144)  { src = s1; dst = d1; K = 512; idx = (blk - 2048) * 256 + threadIdx.x; }
  else if (blk < 10240) { src = s2; dst = d2; K = 512; idx = (blk - 6144) * 256 + threadIdx.x; }
  else if (blk < 10752) { src = s3; dst = d3; K = 512; idx = (blk - 10240) * 256 + threadIdx.x; }
  else                  { src = s4; dst = d4; K = 512; idx = (blk - 10752) * 256 + threadIdx.x; }
  int n = idx / K, k = idx - n * K;
  int lane = (((k & 31) >> 3) << 4) | (n & 15);
  size_t o = ((((size_t)(n >> 4) * (K >> 5)) + (k >> 5)) * 64 + lane) * 8 + (k & 7);
  dst[o] = (bf16_t)src[idx];
}

// ------- merged: embedding gather (A-fragment layout) + dec h0 pack -------
__global__ __launch_bounds__(256) void gather_emb2(
    const int* __restrict__ tokens, const float* __restrict__ table,
    bf16_t* __restrict__ embfrag, const float* __restrict__ dec_h0,
    uint32_t* __restrict__ dec_hf0) {
  int blk = blockIdx.x;
  if (blk < 4096) {
    int idx = blk * 256 + threadIdx.x;    // over (NS*NB)*(NE/8)
    int row = idx >> 5, e0 = (idx & 31) << 3;
    int b = row & 63, s = row >> 6;
    int tok = tokens[b * NS + s];
    const float4* p = (const float4*)(table + (size_t)tok * NE + e0);
    float4 v0 = p[0], v1 = p[1];
    bf16x8 v;
    v[0] = (bf16_t)v0.x; v[1] = (bf16_t)v0.y; v[2] = (bf16_t)v0.z; v[3] = (bf16_t)v0.w;
    v[4] = (bf16_t)v1.x; v[5] = (bf16_t)v1.y; v[6] = (bf16_t)v1.z; v[7] = (bf16_t)v1.w;
    int mt = row >> 4;
    int ks = e0 >> 5;
    int lane = (b & 15) | (((e0 >> 3) & 3) << 4);
    *(bf16x8*)(embfrag + ((size_t)(mt * 8 + ks) * 64 + lane) * 8) = v;
  } else {
    int idx = (blk - 4096) * 256 + threadIdx.x;  // 0..16383 (dword id)
    int b = idx >> 8, jp = idx & 255;
    int j = jp * 2;
    float lo = dec_h0[(size_t)b * NH + j], hi = dec_h0[(size_t)b * NH + j + 1];
    int bg = b >> 4, bl = b & 15, ks = j >> 5;
    int lane = bl | (((j >> 3) & 3) << 4);
    dec_hf0[((size_t)bg * 16 + ks) * 256 + lane * 4 + ((j >> 1) & 3)] = packh(lo, hi);
  }
}

// Tiled GEMM: C[M][N] = Afrag * Bpacked + bias1(+bias2). (blend1/blend2)
template <typename OutT, int KS, int MT>
__global__ __launch_bounds__(256) void gemm_fa2(const bf16_t* __restrict__ A,
                                                const bf16_t* __restrict__ Bp,
                                                OutT* __restrict__ out,
                                                const float* __restrict__ bias1,
                                                const float* __restrict__ bias2,
                                                int N) {
  int lane = threadIdx.x & 63, w = threadIdx.x >> 6;
  int nt = blockIdx.x * 4 + w;
  int mt0 = blockIdx.y * MT;
  bf16x8 bfr[KS];
  const bf16_t* bp = Bp + ((size_t)nt * KS * 64 + lane) * 8;
#pragma unroll
  for (int ks = 0; ks < KS; ++ks) bfr[ks] = *(const bf16x8*)(bp + (size_t)ks * 512);
  int col = (nt << 4) + (lane & 15);
  float bs = bias1[col] + (bias2 ? bias2[col] : 0.f);
  for (int m = 0; m < MT; ++m) {
    int mt = mt0 + m;
    const bf16_t* ap = A + (size_t)mt * (KS * 512) + lane * 8;
    f32x4 acc = {0.f, 0.f, 0.f, 0.f};
#pragma unroll
    for (int ks = 0; ks < KS; ++ks)
      acc = __builtin_amdgcn_mfma_f32_16x16x32_bf16(
          *(const bf16x8*)(ap + (size_t)ks * 512), bfr[ks], acc, 0, 0, 0);
    int rbase = (mt << 4) + ((lane >> 4) << 2);
#pragma unroll
    for (int r = 0; r < 4; ++r)
      out[(size_t)(rbase + r) * N + col] = (OutT)(acc[r] + bs);
  }
}

// Xih GEMM writing the CHAIN-CONSUMPTION layout (r7-proven):
// bf16 addr = ((((mt*16+sl)*2+ct)*4+g)*256 + lane*4 + r, mt = t*4+bg.
__global__ __launch_bounds__(256) void gemm_xih(const bf16_t* __restrict__ A,
                                                const bf16_t* __restrict__ Bp,
                                                bf16_t* __restrict__ out,
                                                const float* __restrict__ b1,
                                                const float* __restrict__ b2) {
  const int KS = 8, MT = 16;
  int lane = threadIdx.x & 63, w = threadIdx.x >> 6;
  int nt = blockIdx.x * 4 + w;        // 0..127
  int mt0 = blockIdx.y * MT;
  bf16x8 bfr[KS];
  const bf16_t* bp = Bp + ((size_t)nt * KS * 64 + lane) * 8;
#pragma unroll
  for (int ks = 0; ks < KS; ++ks) bfr[ks] = *(const bf16x8*)(bp + (size_t)ks * 512);
  int n = (nt << 4) + (lane & 15);
  float bs = b1[n] + b2[n];
  int g = nt >> 5, sl = (nt & 31) >> 1, ct = nt & 1;
  for (int m = 0; m < MT; ++m) {
    int mt = mt0 + m;
    const bf16_t* ap = A + (size_t)mt * (KS * 512) + lane * 8;
    f32x4 acc = {0.f, 0.f, 0.f, 0.f};
#pragma unroll
    for (int ks = 0; ks < KS; ++ks)
      acc = __builtin_amdgcn_mfma_f32_16x16x32_bf16(
          *(const bf16x8*)(ap + (size_t)ks * 512), bfr[ks], acc, 0, 0, 0);
    ushort4 hv;
    hv.x = __builtin_bit_cast(uint16_t, (bf16_t)(acc[0] + bs));
    hv.y = __builtin_bit_cast(uint16_t, (bf16_t)(acc[1] + bs));
    hv.z = __builtin_bit_cast(uint16_t, (bf16_t)(acc[2] + bs));
    hv.w = __builtin_bit_cast(uint16_t, (bf16_t)(acc[3] + bs));
    *(ushort4*)(out + ((((size_t)mt * 16 + sl) * 2 + ct) * 4 + g) * 256 + lane * 4) = hv;
  }
}

// ------- encoder chain: wave-local gates (r7 body) + r4 flag protocol -----
// 64 WGs x 128 thr (2 waves). Wave ct computes ALL 4 gates for its 16 cols
// (cell update per-lane, no LDS gate exchange). One __syncthreads joins the
// two waves (drains vmcnt), then tid0 stores the per-WG flag (r4-style 16
// flags in one line per bg). No other waves, no concurrent pollers.
__global__ __launch_bounds__(128) void lstm_chain_enc(
    const bf16_t* __restrict__ Wp, const bf16_t* __restrict__ xih2,
    uint32_t* __restrict__ hfrag, uint32_t* __restrict__ flags) {
  __shared__ bf16_t wlds[8 * 8192];   // [g*2+ct][16ks][64][8], 128 KB
  int tid = threadIdx.x, lane = tid & 63, ct = tid >> 6;
  int bg = blockIdx.x >> 4, slice = blockIdx.x & 15;

  for (int l = 0; l < 8; ++l) {
    int g = l >> 1, p = l & 1;
    const bf16_t* s = Wp + (size_t)(g * 32 + slice * 2 + p) * 8192;
    for (int i = tid; i < 1024; i += 128)
      *(bf16x8*)(wlds + l * 8192 + (size_t)i * 8) = *(const bf16x8*)(s + (size_t)i * 8);
  }
  __syncthreads();

  const uint64_t* hq = (const uint64_t*)hfrag;
  uint32_t* fl = flags + bg * 16;
  int c = lane & 15, grp = lane >> 4;
  int j = slice * 32 + ct * 16 + c;
  int sub = (j >> 3) & 3, dw = (j >> 1) & 3;
  float cst[4] = {0.f, 0.f, 0.f, 0.f};
  const bf16_t* wb0 = wlds + (size_t)(0 * 2 + ct) * 8192;
  const bf16_t* wb1 = wlds + (size_t)(1 * 2 + ct) * 8192;
  const bf16_t* wb2 = wlds + (size_t)(2 * 2 + ct) * 8192;
  const bf16_t* wb3 = wlds + (size_t)(3 * 2 + ct) * 8192;

  for (int t = 0; t < NS; ++t) {
    // xih prefetch (issued before poll; HBM latency hides under it)
    const uint32_t* xb = (const uint32_t*)xih2 +
        ((((size_t)t * 4 + bg) * 16 + slice) * 2 + ct) * 512 + lane * 2;
    uint2 xg0 = *(const uint2*)(xb);
    uint2 xg1 = *(const uint2*)(xb + 128);
    uint2 xg2 = *(const uint2*)(xb + 256);
    uint2 xg3 = *(const uint2*)(xb + 384);
    if (t > 0) {
      uint32_t tgt = (uint32_t)t;
      bool ok;
      do {
        uint32_t f = tgt;
        if (lane < 16 && lane != (uint32_t)slice) f = aload(fl + lane);
        ok = __all(f >= tgt);
      } while (!ok);
    }
    const uint64_t* hb = hq + ((size_t)t * 4 + bg) * 2048 + lane * 2;
    uint64_t aq[16][2];
#pragma unroll
    for (int ks = 0; ks < 16; ++ks) {
      aq[ks][0] = aload64(hb + (size_t)ks * 128);
      aq[ks][1] = aload64(hb + (size_t)ks * 128 + 1);
    }
    f32x4 a0 = {0.f,0.f,0.f,0.f}, a1 = a0, a2 = a0, a3 = a0;
#pragma unroll
    for (int ks = 0; ks < 16; ++ks) {
      union { uint64_t q[2]; bf16x8 v; } u;
      u.q[0] = aq[ks][0]; u.q[1] = aq[ks][1];
      int o = ks * 512 + lane * 8;
      a0 = __builtin_amdgcn_mfma_f32_16x16x32_bf16(u.v, *(const bf16x8*)(wb0 + o), a0, 0, 0, 0);
      a1 = __builtin_amdgcn_mfma_f32_16x16x32_bf16(u.v, *(const bf16x8*)(wb1 + o), a1, 0, 0, 0);
      a2 = __builtin_amdgcn_mfma_f32_16x16x32_bf16(u.v, *(const bf16x8*)(wb2 + o), a2, 0, 0, 0);
      a3 = __builtin_amdgcn_mfma_f32_16x16x32_bf16(u.v, *(const bf16x8*)(wb3 + o), a3, 0, 0, 0);
    }
    uint32_t hsb = ((uint32_t)(t + 1) * 4 + (uint32_t)bg) * 4096 + slice * 256;
#pragma unroll
    for (int r = 0; r < 4; ++r) {
      float pi = a0[r] + xpick(xg0, r), pf = a1[r] + xpick(xg1, r);
      float pg = a2[r] + xpick(xg2, r), po = a3[r] + xpick(xg3, r);
      float iG = sigm_f(pi), fG = sigm_f(pf), gG = tanh_f(pg), oG = sigm_f(po);
      cst[r] = fG * cst[r] + iG * gG;
      float h = oG * tanh_f(cst[r]);
      uint16_t hv = __builtin_bit_cast(uint16_t, (bf16_t)h);
      uint32_t other = (uint32_t)__shfl_xor((int)(uint32_t)hv, 1, 64);
      if (!(lane & 1)) {   // even col stores packed (j, j+1) dword
        uint32_t dword = (uint32_t)hv | (other << 16);
        astore(hfrag + (size_t)hsb + (((grp * 4 + r) | (sub << 4)) * 4 + dw), dword);
      }
    }
    __syncthreads();   // joins both waves; drains vmcnt -> h ACKed at L3
    if (tid == 0) astore(fl + slice, (uint32_t)(t + 1));
  }
}

// ------- decoder chain: wave-local gates + r4 flag protocol ---------------
__global__ __launch_bounds__(128) void lstm_chain_dec(
    const bf16_t* __restrict__ Wp, const float* __restrict__ bih,
    const float* __restrict__ bhh, uint32_t* __restrict__ hfrag,
    const uint32_t* __restrict__ c0frag, uint32_t* __restrict__ flags) {
  __shared__ bf16_t wlds[8 * 8192];
  int tid = threadIdx.x, lane = tid & 63, ct = tid >> 6;
  int bg = blockIdx.x >> 4, slice = blockIdx.x & 15;

  for (int l = 0; l < 8; ++l) {
    int g = l >> 1, p = l & 1;
    const bf16_t* s = Wp + (size_t)(g * 32 + slice * 2 + p) * 8192;
    for (int i = tid; i < 1024; i += 128)
      *(bf16x8*)(wlds + l * 8192 + (size_t)i * 8) = *(const bf16x8*)(s + (size_t)i * 8);
  }
  __syncthreads();

  const uint64_t* hq = (const uint64_t*)hfrag;
  uint32_t* fl = flags + bg * 16;
  int c = lane & 15, grp = lane >> 4;
  int j = slice * 32 + ct * 16 + c;
  int sub = (j >> 3) & 3, dw = (j >> 1) & 3, half = j & 1;
  float bs0 = bih[0 * NH + j] + bhh[0 * NH + j];
  float bs1 = bih[1 * NH + j] + bhh[1 * NH + j];
  float bs2 = bih[2 * NH + j] + bhh[2 * NH + j];
  float bs3 = bih[3 * NH + j] + bhh[3 * NH + j];
  float cst[4];
#pragma unroll
  for (int r = 0; r < 4; ++r) {
    uint32_t d = c0frag[(size_t)(bg * 16 + slice) * 256 +
                        (((grp * 4 + r) | (sub << 4)) * 4 + dw)];
    cst[r] = half ? bits2f(d >> 16) : bits2f(d & 0xffffu);
  }
  const bf16_t* wb0 = wlds + (size_t)(0 * 2 + ct) * 8192;
  const bf16_t* wb1 = wlds + (size_t)(1 * 2 + ct) * 8192;
  const bf16_t* wb2 = wlds + (size_t)(2 * 2 + ct) * 8192;
  const bf16_t* wb3 = wlds + (size_t)(3 * 2 + ct) * 8192;

  for (int t = 0; t < NTD; ++t) {
    if (t > 0) {
      uint32_t tgt = (uint32_t)t;
      bool ok;
      do {
        uint32_t f = tgt;
        if (lane < 16 && lane != (uint32_t)slice) f = aload(fl + lane);
        ok = __all(f >= tgt);
      } while (!ok);
    }
    const uint64_t* hb = hq + ((size_t)t * 4 + bg) * 2048 + lane * 2;
    uint64_t aq[16][2];
#pragma unroll
    for (int ks = 0; ks < 16; ++ks) {
      aq[ks][0] = aload64(hb + (size_t)ks * 128);
      aq[ks][1] = aload64(hb + (size_t)ks * 128 + 1);
    }
    f32x4 a0 = {0.f,0.f,0.f,0.f}, a1 = a0, a2 = a0, a3 = a0;
#pragma unroll
    for (int ks = 0; ks < 16; ++ks) {
      union { uint64_t q[2]; bf16x8 v; } u;
      u.q[0] = aq[ks][0]; u.q[1] = aq[ks][1];
      int o = ks * 512 + lane * 8;
      a0 = __builtin_amdgcn_mfma_f32_16x16x32_bf16(u.v, *(const bf16x8*)(wb0 + o), a0, 0, 0, 0);
      a1 = __builtin_amdgcn_mfma_f32_16x16x32_bf16(u.v, *(const bf16x8*)(wb1 + o), a1, 0, 0, 0);
      a2 = __builtin_amdgcn_mfma_f32_16x16x32_bf16(u.v, *(const bf16x8*)(wb2 + o), a2, 0, 0, 0);
      a3 = __builtin_amdgcn_mfma_f32_16x16x32_bf16(u.v, *(const bf16x8*)(wb3 + o), a3, 0, 0, 0);
    }
    uint32_t hsb = ((uint32_t)(t + 1) * 4 + (uint32_t)bg) * 4096 + slice * 256;
#pragma unroll
    for (int r = 0; r < 4; ++r) {
      float iG = sigm_f(a0[r] + bs0), fG = sigm_f(a1[r] + bs1);
      float gG = tanh_f(a2[r] + bs2), oG = sigm_f(a3[r] + bs3);
      cst[r] = fG * cst[r] + iG * gG;
      float h = oG * tanh_f(cst[r]);
      uint16_t hv = __builtin_bit_cast(uint16_t, (bf16_t)h);
      uint32_t other = (uint32_t)__shfl_xor((int)(uint32_t)hv, 1, 64);
      if (!(lane & 1)) {
        uint32_t dword = (uint32_t)hv | (other << 16);
        astore(hfrag + (size_t)hsb + (((grp * 4 + r) | (sub << 4)) * 4 + dw), dword);
      }
    }
    __syncthreads();
    if (tid == 0) astore(fl + slice, (uint32_t)(t + 1));
  }
}

// ----- attention v2: coefficients in registers, zero LDS in hot loop ------
__global__ __launch_bounds__(256) void attn_v2(const bf16_t* __restrict__ blend1,
                                               const float* __restrict__ blend2,
                                               const float* __restrict__ vt_w,
                                               float* __restrict__ out) {
  __shared__ float s_u[512], s_red[8];
  int t = blockIdx.x >> 6, b = blockIdx.x & 63;
  int tid = threadIdx.x, lane = tid & 63, wv = tid >> 6;
  int sslot = lane >> 4, wseg = lane & 15;
  int w0 = wseg * 16;

  float vt[16], b2[16];
  {
    const float4* vp = (const float4*)(vt_w + w0);
    const float4* bp = (const float4*)(blend2 + (size_t)(t * 64 + b) * NW + w0);
#pragma unroll
    for (int i = 0; i < 4; ++i) {
      float4 a = vp[i], c = bp[i];
      vt[i * 4 + 0] = a.x; vt[i * 4 + 1] = a.y; vt[i * 4 + 2] = a.z; vt[i * 4 + 3] = a.w;
      b2[i * 4 + 0] = c.x; b2[i * 4 + 1] = c.y; b2[i * 4 + 2] = c.z; b2[i * 4 + 3] = c.w;
    }
  }
  for (int p = 0; p < 32; ++p) {
    int s = p * 16 + wv * 4 + sslot;
    const bf16_t* row = blend1 + ((size_t)s * NB + b) * NW + w0;
    bf16x8 v0 = *(const bf16x8*)(row);
    bf16x8 v1 = *(const bf16x8*)(row + 8);
    float val = 0.f;
#pragma unroll
    for (int k = 0; k < 8; ++k) val += vt[k] * tanh_f((float)v0[k] + b2[k]);
#pragma unroll
    for (int k = 0; k < 8; ++k) val += vt[8 + k] * tanh_f((float)v1[k] + b2[8 + k]);
    val += __shfl_xor(val, 1, 64);
    val += __shfl_xor(val, 2, 64);
    val += __shfl_xor(val, 4, 64);
    val += __shfl_xor(val, 8, 64);
    if (wseg == 0) s_u[s] = val;
  }
  __syncthreads();
  float a = s_u[tid], bb2 = s_u[tid + 256];
  float m = fmaxf(a, bb2);
#pragma unroll
  for (int o = 1; o < 64; o <<= 1) m = fmaxf(m, __shfl_xor(m, o, 64));
  if (lane == 0) s_red[wv] = m;
  __syncthreads();
  m = fmaxf(fmaxf(s_red[0], s_red[1]), fmaxf(s_red[2], s_red[3]));
  float e = __expf(a - m) + __expf(bb2 - m);
#pragma unroll
  for (int o = 1; o < 64; o <<= 1) e += __shfl_xor(e, o, 64);
  if (lane == 0) s_red[4 + wv] = e;
  __syncthreads();
  float lz = m + logf(s_red[4] + s_red[5] + s_red[6] + s_red[7]);
  size_t ob = ((size_t)b * NTD + t) * NS;
  out[ob + tid] = a - lz;
  out[ob + tid + 256] = bb2 - lz;
}

extern "C" void kernel_launch(void* const* d_in, const int* in_sizes, int n_in,
                              void* d_out, int out_size, void* d_ws, size_t ws_size,
                              hipStream_t stream) {
  const int*   tokens    = (const int*)d_in[0];
  const float* dec_h0    = (const float*)d_in[1];
  const float* emb_table = (const float*)d_in[2];
  const float* enc_Wih   = (const float*)d_in[3];
  const float* enc_Whh   = (const float*)d_in[4];
  const float* enc_bih   = (const float*)d_in[5];
  const float* enc_bhh   = (const float*)d_in[6];
  // d_in[7] = dec_Wih: unused (decoder input is the zero vector)
  const float* dec_Whh   = (const float*)d_in[8];
  const float* dec_bih   = (const float*)d_in[9];
  const float* dec_bhh   = (const float*)d_in[10];
  const float* W1_w      = (const float*)d_in[11];
  const float* W1_b      = (const float*)d_in[12];
  const float* W2_w      = (const float*)d_in[13];
  const float* W2_b      = (const float*)d_in[14];
  const float* vt_w      = (const float*)d_in[15];
  // d_in[16] = vt_b: constant shift, invariant under log_softmax
  float* out = (float*)d_out;

  char* w = (char*)d_ws;
  size_t off = 0;
  auto alloc = [&](size_t bytes) {
    size_t o = off;
    off += (bytes + 255) & ~(size_t)255;
    return o;
  };
  bf16_t* embfrag = (bf16_t*)(w + alloc((size_t)NS * NB * NE * 2));           // 16.8 MB
  bf16_t* xih2    = (bf16_t*)(w + alloc((size_t)NS * NB * NG * 2));           // 134 MB
  uint32_t* enc_hf = (uint32_t*)(w + alloc((size_t)(NS + 1) * HSTEP_DW * 4)); // 33.6 MB
  uint32_t* dec_hf = (uint32_t*)(w + alloc((size_t)(NTD + 1) * HSTEP_DW * 4)); // 8.5 MB
  bf16_t* blend1  = (bf16_t*)(w + alloc((size_t)NS * NB * NW * 2));           // 16.8 MB
  float*  blend2  = (float*)(w + alloc((size_t)NTD * NB * NW * 4));           // 8.4 MB
  bf16_t* pWih    = (bf16_t*)(w + alloc((size_t)NG * NE * 2));
  bf16_t* pWhhE   = (bf16_t*)(w + alloc((size_t)NG * NH * 2));
  bf16_t* pWhhD   = (bf16_t*)(w + alloc((size_t)NG * NH * 2));
  bf16_t* pW1     = (bf16_t*)(w + alloc((size_t)NW * NH * 2));
  bf16_t* pW2     = (bf16_t*)(w + alloc((size_t)NW * NH * 2));
  uint32_t* flags = (uint32_t*)(w + alloc(512));   // enc 64 | dec 64 dwords
  (void)ws_size; (void)in_sizes; (void)n_in; (void)out_size;

  // per-call init: flags, enc h_0 = 0
  hipMemsetAsync(flags, 0, 512, stream);
  hipMemsetAsync(enc_hf, 0, HSTEP_DW * 4, stream);

  // all weight packing in one launch
  pack_all<<<11264, 256, 0, stream>>>(enc_Wih, pWih, enc_Whh, pWhhE,
                                      dec_Whh, pWhhD, W1_w, pW1, W2_w, pW2);

  // embedding gather + dec h0 pack in one launch
  gather_emb2<<<4160, 256, 0, stream>>>(tokens, emb_table, embfrag, dec_h0, dec_hf);

  // Xih = emb @ Wih.T + bih + bhh  (chain-consumption layout)
  gemm_xih<<<dim3(128 / 4, 2048 / 16), 256, 0, stream>>>(
      embfrag, pWih, xih2, enc_bih, enc_bhh);

  // encoder chain (wave-local gates, r4 flags, standalone)
  lstm_chain_enc<<<64, 128, 0, stream>>>(pWhhE, xih2, enc_hf, flags);

  // blend1 = enc_states @ W1.T + W1_b (A = enc fragments, skip step 0)
  gemm_fa2<bf16_t, 16, 16><<<dim3(16 / 4, 2048 / 16), 256, 0, stream>>>(
      (const bf16_t*)(enc_hf + HSTEP_DW), pW1, blend1, W1_b, nullptr, NW);

  // decoder chain (wave-local gates, r4 flags, standalone)
  lstm_chain_dec<<<64, 128, 0, stream>>>(pWhhD, dec_bih, dec_bhh, dec_hf,
                                         enc_hf + (size_t)NS * HSTEP_DW,
                                         flags + 64);

  // blend2 = dec_h @ W2.T + W2_b (fp32)
  gemm_fa2<float, 16, 16><<<dim3(16 / 4, 512 / 16), 256, 0, stream>>>(
      (const bf16_t*)(dec_hf + HSTEP_DW), pW2, blend2, W2_b, nullptr, NW);

  // attention + log_softmax -> out [B,T,S]  (register-hoisted coefficients)
  attn_v2<<<NTD * NB, 256, 0, stream>>>(blend1, blend2, vt_w, out);
}

// Round 14
// 2825.981 us; speedup vs baseline: 1.1094x; 1.1094x over previous
//
#include <hip/hip_runtime.h>
#include <hip/hip_bf16.h>
#include <cstdint>
#include <cstddef>

typedef __bf16 bf16_t;
typedef __bf16 bf16x8 __attribute__((ext_vector_type(8)));
typedef float  f32x4  __attribute__((ext_vector_type(4)));

#define NB 64      // batch
#define NS 512     // source sequence length
#define NTD 128    // decoder steps
#define NE 256     // embedding dim
#define NH 512     // hidden dim
#define NG 2048    // 4*H (gates)
#define NW 256     // attention width

// one timestep of h in fragment layout = [4 bg][16 ks][64 lanes][4 dwords]
#define HSTEP_DW 16384u

__device__ __forceinline__ float sigm_f(float x) { return 1.f / (1.f + __expf(-x)); }
__device__ __forceinline__ float tanh_f(float x) {
  float e = __expf(2.f * x);
  return 1.f - 2.f / (e + 1.f);
}
__device__ __forceinline__ float bits2f(uint32_t b16) {
  uint32_t u = b16 << 16;
  return __builtin_bit_cast(float, u);
}
__device__ __forceinline__ uint32_t packh(float a, float b) {
  uint16_t lo = __builtin_bit_cast(uint16_t, (bf16_t)a);
  uint16_t hi = __builtin_bit_cast(uint16_t, (bf16_t)b);
  return (uint32_t)lo | ((uint32_t)hi << 16);
}
__device__ __forceinline__ uint32_t aload(const uint32_t* p) {
  return __hip_atomic_load(p, __ATOMIC_RELAXED, __HIP_MEMORY_SCOPE_AGENT);
}
__device__ __forceinline__ uint64_t aload64(const uint64_t* p) {
  return __hip_atomic_load(p, __ATOMIC_RELAXED, __HIP_MEMORY_SCOPE_AGENT);
}
__device__ __forceinline__ void astore(uint32_t* p, uint32_t v) {
  __hip_atomic_store(p, v, __ATOMIC_RELAXED, __HIP_MEMORY_SCOPE_AGENT);
}

// ------- merged weight packing: all 5 matrices in one launch --------------
// B-fragment order: dst[((ntile*(K/32)+kstep)*64 + lane)*8 + j]
__global__ __launch_bounds__(256) void pack_all(
    const float* __restrict__ s0, bf16_t* __restrict__ d0,   // enc_Wih 2048x256
    const float* __restrict__ s1, bf16_t* __restrict__ d1,   // enc_Whh 2048x512
    const float* __restrict__ s2, bf16_t* __restrict__ d2,   // dec_Whh 2048x512
    const float* __restrict__ s3, bf16_t* __restrict__ d3,   // W1 256x512
    const float* __restrict__ s4, bf16_t* __restrict__ d4) { // W2 256x512
  int blk = blockIdx.x;
  const float* src; bf16_t* dst; int K, idx;
  if (blk < 2048)       { src = s0; dst = d0; K = 256; idx = blk * 256 + threadIdx.x; }
  else if (blk < 6144)  { src = s1; dst = d1; K = 512; idx = (blk - 2048) * 256 + threadIdx.x; }
  else if (blk < 10240) { src = s2; dst = d2; K = 512; idx = (blk - 6144) * 256 + threadIdx.x; }
  else if (blk < 10752) { src = s3; dst = d3; K = 512; idx = (blk - 10240) * 256 + threadIdx.x; }
  else                  { src = s4; dst = d4; K = 512; idx = (blk - 10752) * 256 + threadIdx.x; }
  int n = idx / K, k = idx - n * K;
  int lane = (((k & 31) >> 3) << 4) | (n & 15);
  size_t o = ((((size_t)(n >> 4) * (K >> 5)) + (k >> 5)) * 64 + lane) * 8 + (k & 7);
  dst[o] = (bf16_t)src[idx];
}

// ------- merged: embedding gather (A-fragment layout) + dec h0 pack -------
__global__ __launch_bounds__(256) void gather_emb2(
    const int* __restrict__ tokens, const float* __restrict__ table,
    bf16_t* __restrict__ embfrag, const float* __restrict__ dec_h0,
    uint32_t* __restrict__ dec_hf0) {
  int blk = blockIdx.x;
  if (blk < 4096) {
    int idx = blk * 256 + threadIdx.x;    // over (NS*NB)*(NE/8)
    int row = idx >> 5, e0 = (idx & 31) << 3;
    int b = row & 63, s = row >> 6;
    int tok = tokens[b * NS + s];
    const float4* p = (const float4*)(table + (size_t)tok * NE + e0);
    float4 v0 = p[0], v1 = p[1];
    bf16x8 v;
    v[0] = (bf16_t)v0.x; v[1] = (bf16_t)v0.y; v[2] = (bf16_t)v0.z; v[3] = (bf16_t)v0.w;
    v[4] = (bf16_t)v1.x; v[5] = (bf16_t)v1.y; v[6] = (bf16_t)v1.z; v[7] = (bf16_t)v1.w;
    int mt = row >> 4;
    int ks = e0 >> 5;
    int lane = (b & 15) | (((e0 >> 3) & 3) << 4);
    *(bf16x8*)(embfrag + ((size_t)(mt * 8 + ks) * 64 + lane) * 8) = v;
  } else {
    int idx = (blk - 4096) * 256 + threadIdx.x;  // 0..16383 (dword id)
    int b = idx >> 8, jp = idx & 255;
    int j = jp * 2;
    float lo = dec_h0[(size_t)b * NH + j], hi = dec_h0[(size_t)b * NH + j + 1];
    int bg = b >> 4, bl = b & 15, ks = j >> 5;
    int lane = bl | (((j >> 3) & 3) << 4);
    dec_hf0[((size_t)bg * 16 + ks) * 256 + lane * 4 + ((j >> 1) & 3)] = packh(lo, hi);
  }
}

// ------- xih GEMM with LDS-staged coalesced writes (row layout out) -------
// grid (32,128), 256 thr. Wave w owns n-tile blockIdx.x*4+w; tiles staged in
// LDS then written as full 128B row segments (no write amplification).
__global__ __launch_bounds__(256) void gemm_xih_st(const bf16_t* __restrict__ A,
                                                   const bf16_t* __restrict__ Bp,
                                                   bf16_t* __restrict__ out,
                                                   const float* __restrict__ b1,
                                                   const float* __restrict__ b2) {
  __shared__ bf16_t tile[16][68];
  const int KS = 8, MT = 16;
  int lane = threadIdx.x & 63, w = threadIdx.x >> 6;
  int nt = blockIdx.x * 4 + w;
  int mt0 = blockIdx.y * MT;
  bf16x8 bfr[KS];
  const bf16_t* bp = Bp + ((size_t)nt * KS * 64 + lane) * 8;
#pragma unroll
  for (int ks = 0; ks < KS; ++ks) bfr[ks] = *(const bf16x8*)(bp + (size_t)ks * 512);
  int col = (nt << 4) + (lane & 15);
  float bs = b1[col] + b2[col];
  int row0 = (lane >> 4) << 2;
  int rw = threadIdx.x >> 4, ch = threadIdx.x & 15;
  for (int m = 0; m < MT; ++m) {
    int mt = mt0 + m;
    const bf16_t* ap = A + (size_t)mt * (KS * 512) + lane * 8;
    f32x4 acc = {0.f, 0.f, 0.f, 0.f};
#pragma unroll
    for (int ks = 0; ks < KS; ++ks)
      acc = __builtin_amdgcn_mfma_f32_16x16x32_bf16(
          *(const bf16x8*)(ap + (size_t)ks * 512), bfr[ks], acc, 0, 0, 0);
#pragma unroll
    for (int r = 0; r < 4; ++r)
      tile[row0 + r][w * 16 + (lane & 15)] = (bf16_t)(acc[r] + bs);
    __syncthreads();
    ushort4 v = *(const ushort4*)&tile[rw][ch * 4];
    *(ushort4*)(out + (size_t)(mt * 16 + rw) * NG + blockIdx.x * 64 + ch * 4) = v;
    __syncthreads();
  }
}

// ------- blend1 + blend2 merged, LDS-staged writes -------------------------
// grid (4,160): y<128 -> blend1 (bf16, enc states), y>=128 -> blend2 (fp32).
__global__ __launch_bounds__(256) void gemm_blends(
    const bf16_t* __restrict__ encA, const bf16_t* __restrict__ W1p,
    const float* __restrict__ W1_b, bf16_t* __restrict__ blend1,
    const bf16_t* __restrict__ decA, const bf16_t* __restrict__ W2p,
    const float* __restrict__ W2_b, float* __restrict__ blend2) {
  union { bf16_t t16[16][68]; float t32[16][68]; } sm;
  __shared__ decltype(sm) tile;
  const int KS = 16;
  int lane = threadIdx.x & 63, w = threadIdx.x >> 6;
  int nt = blockIdx.x * 4 + w;
  bool is1 = blockIdx.y < 128;
  int mt0 = (is1 ? blockIdx.y : (blockIdx.y - 128)) * 16;
  const bf16_t* A  = is1 ? encA : decA;
  const bf16_t* Bp = is1 ? W1p : W2p;
  const float* bias = is1 ? W1_b : W2_b;
  bf16x8 bfr[KS];
  const bf16_t* bp = Bp + ((size_t)nt * KS * 64 + lane) * 8;
#pragma unroll
  for (int ks = 0; ks < KS; ++ks) bfr[ks] = *(const bf16x8*)(bp + (size_t)ks * 512);
  int col = (nt << 4) + (lane & 15);
  float bs = bias[col];
  int row0 = (lane >> 4) << 2;
  int rw = threadIdx.x >> 4, ch = threadIdx.x & 15;
  for (int m = 0; m < 16; ++m) {
    int mt = mt0 + m;
    const bf16_t* ap = A + (size_t)mt * (KS * 512) + lane * 8;
    f32x4 acc = {0.f, 0.f, 0.f, 0.f};
#pragma unroll
    for (int ks = 0; ks < KS; ++ks)
      acc = __builtin_amdgcn_mfma_f32_16x16x32_bf16(
          *(const bf16x8*)(ap + (size_t)ks * 512), bfr[ks], acc, 0, 0, 0);
    if (is1) {
#pragma unroll
      for (int r = 0; r < 4; ++r)
        tile.t16[row0 + r][w * 16 + (lane & 15)] = (bf16_t)(acc[r] + bs);
      __syncthreads();
      ushort4 v = *(const ushort4*)&tile.t16[rw][ch * 4];
      *(ushort4*)(blend1 + (size_t)(mt * 16 + rw) * NW + blockIdx.x * 64 + ch * 4) = v;
      __syncthreads();
    } else {
#pragma unroll
      for (int r = 0; r < 4; ++r)
        tile.t32[row0 + r][w * 16 + (lane & 15)] = acc[r] + bs;
      __syncthreads();
      float4 v = *(const float4*)&tile.t32[rw][ch * 4];
      *(float4*)(blend2 + (size_t)(mt * 16 + rw) * NW + blockIdx.x * 64 + ch * 4) = v;
      __syncthreads();
    }
  }
}

// ---------------- encoder chain: EXACT round-4/round-12 protocol ----------
__global__ __launch_bounds__(256) void lstm_chain_enc(
    const bf16_t* __restrict__ Wp, const bf16_t* __restrict__ xih,
    uint32_t* __restrict__ hfrag, uint32_t* __restrict__ flags) {
  __shared__ bf16_t wlds[8 * 8192];      // 128 KB
  __shared__ float gl[4][16][36];        // gate exchange, padded
  int tid = threadIdx.x, lane = tid & 63, wv = tid >> 6;
  int bg = blockIdx.x >> 4, slice = blockIdx.x & 15;

  for (int l = 0; l < 8; ++l) {
    int g = l >> 1, p = l & 1;
    const bf16_t* src = Wp + (size_t)(g * 32 + slice * 2 + p) * 8192;
    bf16_t* dst = wlds + (size_t)l * 8192;
    for (int i = tid; i < 1024; i += 256)
      *(bf16x8*)(dst + (size_t)i * 8) = *(const bf16x8*)(src + (size_t)i * 8);
  }

  int ub = tid >> 4, uj2 = tid & 15;
  int lane_f = ub | ((uj2 >> 2) << 4);
  float c0 = 0.f, c1 = 0.f;
  __syncthreads();

  const uint64_t* hq = (const uint64_t*)hfrag;
  uint32_t* fl = flags + bg * 16;

  for (int t = 0; t < NS; ++t) {
    uint32_t xd[4];
    {
      const uint32_t* xr = (const uint32_t*)xih +
          ((size_t)(t * 64 + bg * 16 + ub)) * 1024 + slice * 16 + uj2;
#pragma unroll
      for (int g = 0; g < 4; ++g) xd[g] = xr[(size_t)g * 256];
    }
    if (t > 0) {
      uint32_t tgt = (uint32_t)t;
      bool ok;
      do {
        uint32_t f = tgt;
        if (lane < 16 && lane != (uint32_t)slice) f = aload(fl + lane);
        ok = __all(f >= tgt);
      } while (!ok);
    }
    const uint64_t* hb = hq + ((size_t)t * 4 + bg) * 2048 + lane * 2;
    uint64_t aq[16][2];
#pragma unroll
    for (int ks = 0; ks < 16; ++ks) {
      aq[ks][0] = aload64(hb + (size_t)ks * 128);
      aq[ks][1] = aload64(hb + (size_t)ks * 128 + 1);
    }
    const bf16_t* wl = wlds + (size_t)(wv * 2) * 8192 + lane * 8;
    f32x4 acc0 = {0.f, 0.f, 0.f, 0.f}, acc1 = {0.f, 0.f, 0.f, 0.f};
#pragma unroll
    for (int ks = 0; ks < 16; ++ks) {
      union { uint64_t q[2]; bf16x8 v; } u;
      u.q[0] = aq[ks][0]; u.q[1] = aq[ks][1];
      acc0 = __builtin_amdgcn_mfma_f32_16x16x32_bf16(
          u.v, *(const bf16x8*)(wl + (size_t)ks * 512), acc0, 0, 0, 0);
      acc1 = __builtin_amdgcn_mfma_f32_16x16x32_bf16(
          u.v, *(const bf16x8*)(wl + 8192 + (size_t)ks * 512), acc1, 0, 0, 0);
    }
    int cc = lane & 15, rb = (lane >> 4) << 2;
#pragma unroll
    for (int r = 0; r < 4; ++r) {
      gl[wv][rb + r][cc] = acc0[r];
      gl[wv][rb + r][16 + cc] = acc1[r];
    }
    __syncthreads();

    float p[4][2];
#pragma unroll
    for (int g = 0; g < 4; ++g) {
      p[g][0] = gl[g][ub][uj2 * 2] + bits2f(xd[g] & 0xffffu);
      p[g][1] = gl[g][ub][uj2 * 2 + 1] + bits2f(xd[g] >> 16);
    }
    float i0 = sigm_f(p[0][0]), f0 = sigm_f(p[1][0]);
    float g0 = tanh_f(p[2][0]), o0 = sigm_f(p[3][0]);
    c0 = f0 * c0 + i0 * g0;
    float h0 = o0 * tanh_f(c0);
    float i1 = sigm_f(p[0][1]), f1 = sigm_f(p[1][1]);
    float g1 = tanh_f(p[2][1]), o1 = sigm_f(p[3][1]);
    c1 = f1 * c1 + i1 * g1;
    float h1 = o1 * tanh_f(c1);
    astore(hfrag + ((size_t)(t + 1) * 4 + bg) * 4096 +
               slice * 256 + lane_f * 4 + (uj2 & 3), packh(h0, h1));
    __syncthreads();   // drains vmcnt -> h stores ACKed at L3
    if (tid == 0) astore(fl + slice, (uint32_t)(t + 1));
  }
}

// ---------------- decoder chain: EXACT round-4/round-12 protocol ----------
__global__ __launch_bounds__(256) void lstm_chain_dec(
    const bf16_t* __restrict__ Wp, const float* __restrict__ bih,
    const float* __restrict__ bhh, uint32_t* __restrict__ hfrag,
    const uint32_t* __restrict__ c0frag, uint32_t* __restrict__ flags) {
  __shared__ bf16_t wlds[8 * 8192];
  __shared__ float gl[4][16][36];
  int tid = threadIdx.x, lane = tid & 63, wv = tid >> 6;
  int bg = blockIdx.x >> 4, slice = blockIdx.x & 15;

  for (int l = 0; l < 8; ++l) {
    int g = l >> 1, p = l & 1;
    const bf16_t* src = Wp + (size_t)(g * 32 + slice * 2 + p) * 8192;
    bf16_t* dst = wlds + (size_t)l * 8192;
    for (int i = tid; i < 1024; i += 256)
      *(bf16x8*)(dst + (size_t)i * 8) = *(const bf16x8*)(src + (size_t)i * 8);
  }
  int ub = tid >> 4, uj2 = tid & 15;
  int j_lo = slice * 32 + uj2 * 2;
  int lane_f = ub | ((uj2 >> 2) << 4);
  uint32_t d = c0frag[((size_t)bg * 16 + slice) * 256 + lane_f * 4 + (uj2 & 3)];
  float c0 = bits2f(d & 0xffffu), c1 = bits2f(d >> 16);
  float bsum[4][2];
#pragma unroll
  for (int g = 0; g < 4; ++g) {
    bsum[g][0] = bih[g * NH + j_lo] + bhh[g * NH + j_lo];
    bsum[g][1] = bih[g * NH + j_lo + 1] + bhh[g * NH + j_lo + 1];
  }
  __syncthreads();

  const uint64_t* hq = (const uint64_t*)hfrag;
  uint32_t* fl = flags + bg * 16;

  for (int t = 0; t < NTD; ++t) {
    if (t > 0) {
      uint32_t tgt = (uint32_t)t;
      bool ok;
      do {
        uint32_t f = tgt;
        if (lane < 16 && lane != (uint32_t)slice) f = aload(fl + lane);
        ok = __all(f >= tgt);
      } while (!ok);
    }
    const uint64_t* hb = hq + ((size_t)t * 4 + bg) * 2048 + lane * 2;
    uint64_t aq[16][2];
#pragma unroll
    for (int ks = 0; ks < 16; ++ks) {
      aq[ks][0] = aload64(hb + (size_t)ks * 128);
      aq[ks][1] = aload64(hb + (size_t)ks * 128 + 1);
    }
    const bf16_t* wl = wlds + (size_t)(wv * 2) * 8192 + lane * 8;
    f32x4 acc0 = {0.f, 0.f, 0.f, 0.f}, acc1 = {0.f, 0.f, 0.f, 0.f};
#pragma unroll
    for (int ks = 0; ks < 16; ++ks) {
      union { uint64_t q[2]; bf16x8 v; } u;
      u.q[0] = aq[ks][0]; u.q[1] = aq[ks][1];
      acc0 = __builtin_amdgcn_mfma_f32_16x16x32_bf16(
          u.v, *(const bf16x8*)(wl + (size_t)ks * 512), acc0, 0, 0, 0);
      acc1 = __builtin_amdgcn_mfma_f32_16x16x32_bf16(
          u.v, *(const bf16x8*)(wl + 8192 + (size_t)ks * 512), acc1, 0, 0, 0);
    }
    int cc = lane & 15, rb = (lane >> 4) << 2;
#pragma unroll
    for (int r = 0; r < 4; ++r) {
      gl[wv][rb + r][cc] = acc0[r];
      gl[wv][rb + r][16 + cc] = acc1[r];
    }
    __syncthreads();

    float p[4][2];
#pragma unroll
    for (int g = 0; g < 4; ++g) {
      p[g][0] = gl[g][ub][uj2 * 2] + bsum[g][0];
      p[g][1] = gl[g][ub][uj2 * 2 + 1] + bsum[g][1];
    }
    float i0 = sigm_f(p[0][0]), f0 = sigm_f(p[1][0]);
    float g0 = tanh_f(p[2][0]), o0 = sigm_f(p[3][0]);
    c0 = f0 * c0 + i0 * g0;
    float h0 = o0 * tanh_f(c0);
    float i1 = sigm_f(p[0][1]), f1 = sigm_f(p[1][1]);
    float g1 = tanh_f(p[2][1]), o1 = sigm_f(p[3][1]);
    c1 = f1 * c1 + i1 * g1;
    float h1 = o1 * tanh_f(c1);
    astore(hfrag + ((size_t)(t + 1) * 4 + bg) * 4096 +
               slice * 256 + lane_f * 4 + (uj2 & 3), packh(h0, h1));
    __syncthreads();
    if (tid == 0) astore(fl + slice, (uint32_t)(t + 1));
  }
}

// ----- attention v2: coefficients in registers, zero LDS in hot loop ------
__global__ __launch_bounds__(256) void attn_v2(const bf16_t* __restrict__ blend1,
                                               const float* __restrict__ blend2,
                                               const float* __restrict__ vt_w,
                                               float* __restrict__ out) {
  __shared__ float s_u[512], s_red[8];
  int t = blockIdx.x >> 6, b = blockIdx.x & 63;
  int tid = threadIdx.x, lane = tid & 63, wv = tid >> 6;
  int sslot = lane >> 4, wseg = lane & 15;
  int w0 = wseg * 16;

  float vt[16], b2[16];
  {
    const float4* vp = (const float4*)(vt_w + w0);
    const float4* bp = (const float4*)(blend2 + (size_t)(t * 64 + b) * NW + w0);
#pragma unroll
    for (int i = 0; i < 4; ++i) {
      float4 a = vp[i], c = bp[i];
      vt[i * 4 + 0] = a.x; vt[i * 4 + 1] = a.y; vt[i * 4 + 2] = a.z; vt[i * 4 + 3] = a.w;
      b2[i * 4 + 0] = c.x; b2[i * 4 + 1] = c.y; b2[i * 4 + 2] = c.z; b2[i * 4 + 3] = c.w;
    }
  }
  for (int p = 0; p < 32; ++p) {
    int s = p * 16 + wv * 4 + sslot;
    const bf16_t* row = blend1 + ((size_t)s * NB + b) * NW + w0;
    bf16x8 v0 = *(const bf16x8*)(row);
    bf16x8 v1 = *(const bf16x8*)(row + 8);
    float val = 0.f;
#pragma unroll
    for (int k = 0; k < 8; ++k) val += vt[k] * tanh_f((float)v0[k] + b2[k]);
#pragma unroll
    for (int k = 0; k < 8; ++k) val += vt[8 + k] * tanh_f((float)v1[k] + b2[8 + k]);
    val += __shfl_xor(val, 1, 64);
    val += __shfl_xor(val, 2, 64);
    val += __shfl_xor(val, 4, 64);
    val += __shfl_xor(val, 8, 64);
    if (wseg == 0) s_u[s] = val;
  }
  __syncthreads();
  float a = s_u[tid], bb2 = s_u[tid + 256];
  float m = fmaxf(a, bb2);
#pragma unroll
  for (int o = 1; o < 64; o <<= 1) m = fmaxf(m, __shfl_xor(m, o, 64));
  if (lane == 0) s_red[wv] = m;
  __syncthreads();
  m = fmaxf(fmaxf(s_red[0], s_red[1]), fmaxf(s_red[2], s_red[3]));
  float e = __expf(a - m) + __expf(bb2 - m);
#pragma unroll
  for (int o = 1; o < 64; o <<= 1) e += __shfl_xor(e, o, 64);
  if (lane == 0) s_red[4 + wv] = e;
  __syncthreads();
  float lz = m + logf(s_red[4] + s_red[5] + s_red[6] + s_red[7]);
  size_t ob = ((size_t)b * NTD + t) * NS;
  out[ob + tid] = a - lz;
  out[ob + tid + 256] = bb2 - lz;
}

extern "C" void kernel_launch(void* const* d_in, const int* in_sizes, int n_in,
                              void* d_out, int out_size, void* d_ws, size_t ws_size,
                              hipStream_t stream) {
  const int*   tokens    = (const int*)d_in[0];
  const float* dec_h0    = (const float*)d_in[1];
  const float* emb_table = (const float*)d_in[2];
  const float* enc_Wih   = (const float*)d_in[3];
  const float* enc_Whh   = (const float*)d_in[4];
  const float* enc_bih   = (const float*)d_in[5];
  const float* enc_bhh   = (const float*)d_in[6];
  // d_in[7] = dec_Wih: unused (decoder input is the zero vector)
  const float* dec_Whh   = (const float*)d_in[8];
  const float* dec_bih   = (const float*)d_in[9];
  const float* dec_bhh   = (const float*)d_in[10];
  const float* W1_w      = (const float*)d_in[11];
  const float* W1_b      = (const float*)d_in[12];
  const float* W2_w      = (const float*)d_in[13];
  const float* W2_b      = (const float*)d_in[14];
  const float* vt_w      = (const float*)d_in[15];
  // d_in[16] = vt_b: constant shift, invariant under log_softmax
  float* out = (float*)d_out;

  char* w = (char*)d_ws;
  size_t off = 0;
  auto alloc = [&](size_t bytes) {
    size_t o = off;
    off += (bytes + 255) & ~(size_t)255;
    return o;
  };
  bf16_t* embfrag = (bf16_t*)(w + alloc((size_t)NS * NB * NE * 2));           // 16.8 MB
  bf16_t* xih     = (bf16_t*)(w + alloc((size_t)NS * NB * NG * 2));           // 134 MB
  uint32_t* enc_hf = (uint32_t*)(w + alloc((size_t)(NS + 1) * HSTEP_DW * 4)); // 33.6 MB
  uint32_t* dec_hf = (uint32_t*)(w + alloc((size_t)(NTD + 1) * HSTEP_DW * 4)); // 8.5 MB
  bf16_t* blend1  = (bf16_t*)(w + alloc((size_t)NS * NB * NW * 2));           // 16.8 MB
  float*  blend2  = (float*)(w + alloc((size_t)NTD * NB * NW * 4));           // 8.4 MB
  bf16_t* pWih    = (bf16_t*)(w + alloc((size_t)NG * NE * 2));
  bf16_t* pWhhE   = (bf16_t*)(w + alloc((size_t)NG * NH * 2));
  bf16_t* pWhhD   = (bf16_t*)(w + alloc((size_t)NG * NH * 2));
  bf16_t* pW1     = (bf16_t*)(w + alloc((size_t)NW * NH * 2));
  bf16_t* pW2     = (bf16_t*)(w + alloc((size_t)NW * NH * 2));
  uint32_t* flags = (uint32_t*)(w + alloc(512));   // enc 64 | dec 64 dwords
  (void)ws_size; (void)in_sizes; (void)n_in; (void)out_size;

  // per-call init: flags, enc h_0 = 0
  hipMemsetAsync(flags, 0, 512, stream);
  hipMemsetAsync(enc_hf, 0, HSTEP_DW * 4, stream);

  // all weight packing in one launch
  pack_all<<<11264, 256, 0, stream>>>(enc_Wih, pWih, enc_Whh, pWhhE,
                                      dec_Whh, pWhhD, W1_w, pW1, W2_w, pW2);

  // embedding gather + dec h0 pack in one launch
  gather_emb2<<<4160, 256, 0, stream>>>(tokens, emb_table, embfrag, dec_h0, dec_hf);

  // Xih = emb @ Wih.T + bih + bhh  (row layout, LDS-staged coalesced writes)
  gemm_xih_st<<<dim3(32, 128), 256, 0, stream>>>(embfrag, pWih, xih,
                                                 enc_bih, enc_bhh);

  // encoder chain (r12 protocol, standalone)
  lstm_chain_enc<<<64, 256, 0, stream>>>(pWhhE, xih, enc_hf, flags);

  // decoder chain (r12 protocol, standalone); c0 = last encoder h
  lstm_chain_dec<<<64, 256, 0, stream>>>(pWhhD, dec_bih, dec_bhh, dec_hf,
                                         enc_hf + (size_t)NS * HSTEP_DW,
                                         flags + 64);

  // blend1 + blend2 in one launch (LDS-staged coalesced writes)
  gemm_blends<<<dim3(4, 160), 256, 0, stream>>>(
      (const bf16_t*)(enc_hf + HSTEP_DW), pW1, W1_b, blend1,
      (const bf16_t*)(dec_hf + HSTEP_DW), pW2, W2_b, blend2);

  // attention + log_softmax -> out [B,T,S]  (register-hoisted coefficients)
  attn_v2<<<NTD * NB, 256, 0, stream>>>(blend1, blend2, vt_w, out);
}

// Round 15
// 2659.605 us; speedup vs baseline: 1.1788x; 1.0626x over previous
//
#include <hip/hip_runtime.h>
#include <hip/hip_bf16.h>
#include <cstdint>
#include <cstddef>

typedef __bf16 bf16_t;
typedef __bf16 bf16x8 __attribute__((ext_vector_type(8)));
typedef float  f32x4  __attribute__((ext_vector_type(4)));

#define NB 64      // batch
#define NS 512     // source sequence length
#define NTD 128    // decoder steps
#define NE 256     // embedding dim
#define NH 512     // hidden dim
#define NG 2048    // 4*H (gates)
#define NW 256     // attention width

// one timestep of h in fragment layout = [4 bg][16 ks][64 lanes][4 dwords]
#define HSTEP_DW 16384u

__device__ __forceinline__ float sigm_f(float x) { return 1.f / (1.f + __expf(-x)); }
__device__ __forceinline__ float tanh_f(float x) {
  float e = __expf(2.f * x);
  return 1.f - 2.f / (e + 1.f);
}
__device__ __forceinline__ float bits2f(uint32_t b16) {
  uint32_t u = b16 << 16;
  return __builtin_bit_cast(float, u);
}
__device__ __forceinline__ uint32_t packh(float a, float b) {
  uint16_t lo = __builtin_bit_cast(uint16_t, (bf16_t)a);
  uint16_t hi = __builtin_bit_cast(uint16_t, (bf16_t)b);
  return (uint32_t)lo | ((uint32_t)hi << 16);
}
__device__ __forceinline__ uint32_t aload(const uint32_t* p) {
  return __hip_atomic_load(p, __ATOMIC_RELAXED, __HIP_MEMORY_SCOPE_AGENT);
}
__device__ __forceinline__ uint64_t aload64(const uint64_t* p) {
  return __hip_atomic_load(p, __ATOMIC_RELAXED, __HIP_MEMORY_SCOPE_AGENT);
}
__device__ __forceinline__ void astore(uint32_t* p, uint32_t v) {
  __hip_atomic_store(p, v, __ATOMIC_RELAXED, __HIP_MEMORY_SCOPE_AGENT);
}

// ------- merged weight packing: all 5 matrices in one launch --------------
// B-fragment order: dst[((ntile*(K/32)+kstep)*64 + lane)*8 + j]
__global__ __launch_bounds__(256) void pack_all(
    const float* __restrict__ s0, bf16_t* __restrict__ d0,   // enc_Wih 2048x256
    const float* __restrict__ s1, bf16_t* __restrict__ d1,   // enc_Whh 2048x512
    const float* __restrict__ s2, bf16_t* __restrict__ d2,   // dec_Whh 2048x512
    const float* __restrict__ s3, bf16_t* __restrict__ d3,   // W1 256x512
    const float* __restrict__ s4, bf16_t* __restrict__ d4) { // W2 256x512
  int blk = blockIdx.x;
  const float* src; bf16_t* dst; int K, idx;
  if (blk < 2048)       { src = s0; dst = d0; K = 256; idx = blk * 256 + threadIdx.x; }
  else if (blk < 6144)  { src = s1; dst = d1; K = 512; idx = (blk - 2048) * 256 + threadIdx.x; }
  else if (blk < 10240) { src = s2; dst = d2; K = 512; idx = (blk - 6144) * 256 + threadIdx.x; }
  else if (blk < 10752) { src = s3; dst = d3; K = 512; idx = (blk - 10240) * 256 + threadIdx.x; }
  else                  { src = s4; dst = d4; K = 512; idx = (blk - 10752) * 256 + threadIdx.x; }
  int n = idx / K, k = idx - n * K;
  int lane = (((k & 31) >> 3) << 4) | (n & 15);
  size_t o = ((((size_t)(n >> 4) * (K >> 5)) + (k >> 5)) * 64 + lane) * 8 + (k & 7);
  dst[o] = (bf16_t)src[idx];
}

// ------- merged: embedding gather (A-fragment layout) + dec h0 pack -------
__global__ __launch_bounds__(256) void gather_emb2(
    const int* __restrict__ tokens, const float* __restrict__ table,
    bf16_t* __restrict__ embfrag, const float* __restrict__ dec_h0,
    uint32_t* __restrict__ dec_hf0) {
  int blk = blockIdx.x;
  if (blk < 4096) {
    int idx = blk * 256 + threadIdx.x;    // over (NS*NB)*(NE/8)
    int row = idx >> 5, e0 = (idx & 31) << 3;
    int b = row & 63, s = row >> 6;
    int tok = tokens[b * NS + s];
    const float4* p = (const float4*)(table + (size_t)tok * NE + e0);
    float4 v0 = p[0], v1 = p[1];
    bf16x8 v;
    v[0] = (bf16_t)v0.x; v[1] = (bf16_t)v0.y; v[2] = (bf16_t)v0.z; v[3] = (bf16_t)v0.w;
    v[4] = (bf16_t)v1.x; v[5] = (bf16_t)v1.y; v[6] = (bf16_t)v1.z; v[7] = (bf16_t)v1.w;
    int mt = row >> 4;
    int ks = e0 >> 5;
    int lane = (b & 15) | (((e0 >> 3) & 3) << 4);
    *(bf16x8*)(embfrag + ((size_t)(mt * 8 + ks) * 64 + lane) * 8) = v;
  } else {
    int idx = (blk - 4096) * 256 + threadIdx.x;  // 0..16383 (dword id)
    int b = idx >> 8, jp = idx & 255;
    int j = jp * 2;
    float lo = dec_h0[(size_t)b * NH + j], hi = dec_h0[(size_t)b * NH + j + 1];
    int bg = b >> 4, bl = b & 15, ks = j >> 5;
    int lane = bl | (((j >> 3) & 3) << 4);
    dec_hf0[((size_t)bg * 16 + ks) * 256 + lane * 4 + ((j >> 1) & 3)] = packh(lo, hi);
  }
}

// ------- blend1 + blend2 merged, LDS-staged writes -------------------------
// grid (4,160): y<128 -> blend1 (bf16, enc states), y>=128 -> blend2 (fp32).
__global__ __launch_bounds__(256) void gemm_blends(
    const bf16_t* __restrict__ encA, const bf16_t* __restrict__ W1p,
    const float* __restrict__ W1_b, bf16_t* __restrict__ blend1,
    const bf16_t* __restrict__ decA, const bf16_t* __restrict__ W2p,
    const float* __restrict__ W2_b, float* __restrict__ blend2) {
  union SMU { bf16_t t16[16][68]; float t32[16][68]; };
  __shared__ SMU tile;
  const int KS = 16;
  int lane = threadIdx.x & 63, w = threadIdx.x >> 6;
  int nt = blockIdx.x * 4 + w;
  bool is1 = blockIdx.y < 128;
  int mt0 = (is1 ? blockIdx.y : (blockIdx.y - 128)) * 16;
  const bf16_t* A  = is1 ? encA : decA;
  const bf16_t* Bp = is1 ? W1p : W2p;
  const float* bias = is1 ? W1_b : W2_b;
  bf16x8 bfr[KS];
  const bf16_t* bp = Bp + ((size_t)nt * KS * 64 + lane) * 8;
#pragma unroll
  for (int ks = 0; ks < KS; ++ks) bfr[ks] = *(const bf16x8*)(bp + (size_t)ks * 512);
  int col = (nt << 4) + (lane & 15);
  float bs = bias[col];
  int row0 = (lane >> 4) << 2;
  int rw = threadIdx.x >> 4, ch = threadIdx.x & 15;
  for (int m = 0; m < 16; ++m) {
    int mt = mt0 + m;
    const bf16_t* ap = A + (size_t)mt * (KS * 512) + lane * 8;
    f32x4 acc = {0.f, 0.f, 0.f, 0.f};
#pragma unroll
    for (int ks = 0; ks < KS; ++ks)
      acc = __builtin_amdgcn_mfma_f32_16x16x32_bf16(
          *(const bf16x8*)(ap + (size_t)ks * 512), bfr[ks], acc, 0, 0, 0);
    if (is1) {
#pragma unroll
      for (int r = 0; r < 4; ++r)
        tile.t16[row0 + r][w * 16 + (lane & 15)] = (bf16_t)(acc[r] + bs);
      __syncthreads();
      ushort4 v = *(const ushort4*)&tile.t16[rw][ch * 4];
      *(ushort4*)(blend1 + (size_t)(mt * 16 + rw) * NW + blockIdx.x * 64 + ch * 4) = v;
      __syncthreads();
    } else {
#pragma unroll
      for (int r = 0; r < 4; ++r)
        tile.t32[row0 + r][w * 16 + (lane & 15)] = acc[r] + bs;
      __syncthreads();
      float4 v = *(const float4*)&tile.t32[rw][ch * 4];
      *(float4*)(blend2 + (size_t)(mt * 16 + rw) * NW + blockIdx.x * 64 + ch * 4) = v;
      __syncthreads();
    }
  }
}

// ------- encoder chain: r12 protocol + FUSED x@Wih.T (acc-init) -----------
// Wave wv = gate wv over this slice's 32 cols. Wih B-fragments (2 ntiles x
// 8 ksteps) live in 64 VGPRs; emb A-fragments for step t are h-independent
// (loaded before the poll; the 16 init-MFMAs hide under the poll window).
__global__ __launch_bounds__(256) void lstm_chain_enc(
    const bf16_t* __restrict__ Wp, const bf16_t* __restrict__ Wihp,
    const bf16_t* __restrict__ embfrag, const float* __restrict__ bih,
    const float* __restrict__ bhh, uint32_t* __restrict__ hfrag,
    uint32_t* __restrict__ flags) {
  __shared__ bf16_t wlds[8 * 8192];      // 128 KB (Whh slice)
  __shared__ float gl[4][16][36];        // gate exchange, padded
  int tid = threadIdx.x, lane = tid & 63, wv = tid >> 6;
  int bg = blockIdx.x >> 4, slice = blockIdx.x & 15;

  for (int l = 0; l < 8; ++l) {
    int g = l >> 1, p = l & 1;
    const bf16_t* src = Wp + (size_t)(g * 32 + slice * 2 + p) * 8192;
    bf16_t* dst = wlds + (size_t)l * 8192;
    for (int i = tid; i < 1024; i += 256)
      *(bf16x8*)(dst + (size_t)i * 8) = *(const bf16x8*)(src + (size_t)i * 8);
  }
  // Wih fragments -> registers: gate wv, ntiles wv*32 + slice*2 + {0,1}
  bf16x8 xf0[8], xf1[8];
  {
    int nt0 = wv * 32 + slice * 2;
    const bf16_t* p0 = Wihp + (((size_t)nt0 * 8) * 64 + lane) * 8;
    const bf16_t* p1 = Wihp + (((size_t)(nt0 + 1) * 8) * 64 + lane) * 8;
#pragma unroll
    for (int ks = 0; ks < 8; ++ks) {
      xf0[ks] = *(const bf16x8*)(p0 + (size_t)ks * 512);
      xf1[ks] = *(const bf16x8*)(p1 + (size_t)ks * 512);
    }
  }

  int ub = tid >> 4, uj2 = tid & 15;
  int j_lo = slice * 32 + uj2 * 2;
  int lane_f = ub | ((uj2 >> 2) << 4);
  float c0 = 0.f, c1 = 0.f;
  float bsum[4][2];
#pragma unroll
  for (int g = 0; g < 4; ++g) {
    bsum[g][0] = bih[g * NH + j_lo] + bhh[g * NH + j_lo];
    bsum[g][1] = bih[g * NH + j_lo + 1] + bhh[g * NH + j_lo + 1];
  }
  __syncthreads();

  const uint64_t* hq = (const uint64_t*)hfrag;
  uint32_t* fl = flags + bg * 16;

  for (int t = 0; t < NS; ++t) {
    // emb A-fragments for step t (no h dependency; issued before poll)
    bf16x8 ea[8];
    const bf16_t* eb = embfrag + (((size_t)(t * 4 + bg) * 8) * 64 + lane) * 8;
#pragma unroll
    for (int ks = 0; ks < 8; ++ks) ea[ks] = *(const bf16x8*)(eb + (size_t)ks * 512);
    if (t > 0) {
      uint32_t tgt = (uint32_t)t;
      bool ok;
      do {
        uint32_t f = tgt;
        if (lane < 16 && lane != (uint32_t)slice) f = aload(fl + lane);
        ok = __all(f >= tgt);
      } while (!ok);
    }
    // init accumulators with x@Wih.T (replaces the precomputed xih stream)
    f32x4 acc0 = {0.f, 0.f, 0.f, 0.f}, acc1 = {0.f, 0.f, 0.f, 0.f};
#pragma unroll
    for (int ks = 0; ks < 8; ++ks) {
      acc0 = __builtin_amdgcn_mfma_f32_16x16x32_bf16(ea[ks], xf0[ks], acc0, 0, 0, 0);
      acc1 = __builtin_amdgcn_mfma_f32_16x16x32_bf16(ea[ks], xf1[ks], acc1, 0, 0, 0);
    }
    const uint64_t* hb = hq + ((size_t)t * 4 + bg) * 2048 + lane * 2;
    uint64_t aq[16][2];
#pragma unroll
    for (int ks = 0; ks < 16; ++ks) {
      aq[ks][0] = aload64(hb + (size_t)ks * 128);
      aq[ks][1] = aload64(hb + (size_t)ks * 128 + 1);
    }
    const bf16_t* wl = wlds + (size_t)(wv * 2) * 8192 + lane * 8;
#pragma unroll
    for (int ks = 0; ks < 16; ++ks) {
      union { uint64_t q[2]; bf16x8 v; } u;
      u.q[0] = aq[ks][0]; u.q[1] = aq[ks][1];
      acc0 = __builtin_amdgcn_mfma_f32_16x16x32_bf16(
          u.v, *(const bf16x8*)(wl + (size_t)ks * 512), acc0, 0, 0, 0);
      acc1 = __builtin_amdgcn_mfma_f32_16x16x32_bf16(
          u.v, *(const bf16x8*)(wl + 8192 + (size_t)ks * 512), acc1, 0, 0, 0);
    }
    int cc = lane & 15, rb = (lane >> 4) << 2;
#pragma unroll
    for (int r = 0; r < 4; ++r) {
      gl[wv][rb + r][cc] = acc0[r];
      gl[wv][rb + r][16 + cc] = acc1[r];
    }
    __syncthreads();

    float p[4][2];
#pragma unroll
    for (int g = 0; g < 4; ++g) {
      p[g][0] = gl[g][ub][uj2 * 2] + bsum[g][0];
      p[g][1] = gl[g][ub][uj2 * 2 + 1] + bsum[g][1];
    }
    float i0 = sigm_f(p[0][0]), f0 = sigm_f(p[1][0]);
    float g0 = tanh_f(p[2][0]), o0 = sigm_f(p[3][0]);
    c0 = f0 * c0 + i0 * g0;
    float h0 = o0 * tanh_f(c0);
    float i1 = sigm_f(p[0][1]), f1 = sigm_f(p[1][1]);
    float g1 = tanh_f(p[2][1]), o1 = sigm_f(p[3][1]);
    c1 = f1 * c1 + i1 * g1;
    float h1 = o1 * tanh_f(c1);
    astore(hfrag + ((size_t)(t + 1) * 4 + bg) * 4096 +
               slice * 256 + lane_f * 4 + (uj2 & 3), packh(h0, h1));
    __syncthreads();   // drains vmcnt -> h stores ACKed at L3
    if (tid == 0) astore(fl + slice, (uint32_t)(t + 1));
  }
}

// ---------------- decoder chain: EXACT round-4/round-12 protocol ----------
__global__ __launch_bounds__(256) void lstm_chain_dec(
    const bf16_t* __restrict__ Wp, const float* __restrict__ bih,
    const float* __restrict__ bhh, uint32_t* __restrict__ hfrag,
    const uint32_t* __restrict__ c0frag, uint32_t* __restrict__ flags) {
  __shared__ bf16_t wlds[8 * 8192];
  __shared__ float gl[4][16][36];
  int tid = threadIdx.x, lane = tid & 63, wv = tid >> 6;
  int bg = blockIdx.x >> 4, slice = blockIdx.x & 15;

  for (int l = 0; l < 8; ++l) {
    int g = l >> 1, p = l & 1;
    const bf16_t* src = Wp + (size_t)(g * 32 + slice * 2 + p) * 8192;
    bf16_t* dst = wlds + (size_t)l * 8192;
    for (int i = tid; i < 1024; i += 256)
      *(bf16x8*)(dst + (size_t)i * 8) = *(const bf16x8*)(src + (size_t)i * 8);
  }
  int ub = tid >> 4, uj2 = tid & 15;
  int j_lo = slice * 32 + uj2 * 2;
  int lane_f = ub | ((uj2 >> 2) << 4);
  uint32_t d = c0frag[((size_t)bg * 16 + slice) * 256 + lane_f * 4 + (uj2 & 3)];
  float c0 = bits2f(d & 0xffffu), c1 = bits2f(d >> 16);
  float bsum[4][2];
#pragma unroll
  for (int g = 0; g < 4; ++g) {
    bsum[g][0] = bih[g * NH + j_lo] + bhh[g * NH + j_lo];
    bsum[g][1] = bih[g * NH + j_lo + 1] + bhh[g * NH + j_lo + 1];
  }
  __syncthreads();

  const uint64_t* hq = (const uint64_t*)hfrag;
  uint32_t* fl = flags + bg * 16;

  for (int t = 0; t < NTD; ++t) {
    if (t > 0) {
      uint32_t tgt = (uint32_t)t;
      bool ok;
      do {
        uint32_t f = tgt;
        if (lane < 16 && lane != (uint32_t)slice) f = aload(fl + lane);
        ok = __all(f >= tgt);
      } while (!ok);
    }
    const uint64_t* hb = hq + ((size_t)t * 4 + bg) * 2048 + lane * 2;
    uint64_t aq[16][2];
#pragma unroll
    for (int ks = 0; ks < 16; ++ks) {
      aq[ks][0] = aload64(hb + (size_t)ks * 128);
      aq[ks][1] = aload64(hb + (size_t)ks * 128 + 1);
    }
    const bf16_t* wl = wlds + (size_t)(wv * 2) * 8192 + lane * 8;
    f32x4 acc0 = {0.f, 0.f, 0.f, 0.f}, acc1 = {0.f, 0.f, 0.f, 0.f};
#pragma unroll
    for (int ks = 0; ks < 16; ++ks) {
      union { uint64_t q[2]; bf16x8 v; } u;
      u.q[0] = aq[ks][0]; u.q[1] = aq[ks][1];
      acc0 = __builtin_amdgcn_mfma_f32_16x16x32_bf16(
          u.v, *(const bf16x8*)(wl + (size_t)ks * 512), acc0, 0, 0, 0);
      acc1 = __builtin_amdgcn_mfma_f32_16x16x32_bf16(
          u.v, *(const bf16x8*)(wl + 8192 + (size_t)ks * 512), acc1, 0, 0, 0);
    }
    int cc = lane & 15, rb = (lane >> 4) << 2;
#pragma unroll
    for (int r = 0; r < 4; ++r) {
      gl[wv][rb + r][cc] = acc0[r];
      gl[wv][rb + r][16 + cc] = acc1[r];
    }
    __syncthreads();

    float p[4][2];
#pragma unroll
    for (int g = 0; g < 4; ++g) {
      p[g][0] = gl[g][ub][uj2 * 2] + bsum[g][0];
      p[g][1] = gl[g][ub][uj2 * 2 + 1] + bsum[g][1];
    }
    float i0 = sigm_f(p[0][0]), f0 = sigm_f(p[1][0]);
    float g0 = tanh_f(p[2][0]), o0 = sigm_f(p[3][0]);
    c0 = f0 * c0 + i0 * g0;
    float h0 = o0 * tanh_f(c0);
    float i1 = sigm_f(p[0][1]), f1 = sigm_f(p[1][1]);
    float g1 = tanh_f(p[2][1]), o1 = sigm_f(p[3][1]);
    c1 = f1 * c1 + i1 * g1;
    float h1 = o1 * tanh_f(c1);
    astore(hfrag + ((size_t)(t + 1) * 4 + bg) * 4096 +
               slice * 256 + lane_f * 4 + (uj2 & 3), packh(h0, h1));
    __syncthreads();
    if (tid == 0) astore(fl + slice, (uint32_t)(t + 1));
  }
}

// ----- attention v2: coefficients in registers, zero LDS in hot loop ------
__global__ __launch_bounds__(256) void attn_v2(const bf16_t* __restrict__ blend1,
                                               const float* __restrict__ blend2,
                                               const float* __restrict__ vt_w,
                                               float* __restrict__ out) {
  __shared__ float s_u[512], s_red[8];
  int t = blockIdx.x >> 6, b = blockIdx.x & 63;
  int tid = threadIdx.x, lane = tid & 63, wv = tid >> 6;
  int sslot = lane >> 4, wseg = lane & 15;
  int w0 = wseg * 16;

  float vt[16], b2[16];
  {
    const float4* vp = (const float4*)(vt_w + w0);
    const float4* bp = (const float4*)(blend2 + (size_t)(t * 64 + b) * NW + w0);
#pragma unroll
    for (int i = 0; i < 4; ++i) {
      float4 a = vp[i], c = bp[i];
      vt[i * 4 + 0] = a.x; vt[i * 4 + 1] = a.y; vt[i * 4 + 2] = a.z; vt[i * 4 + 3] = a.w;
      b2[i * 4 + 0] = c.x; b2[i * 4 + 1] = c.y; b2[i * 4 + 2] = c.z; b2[i * 4 + 3] = c.w;
    }
  }
  for (int p = 0; p < 32; ++p) {
    int s = p * 16 + wv * 4 + sslot;
    const bf16_t* row = blend1 + ((size_t)s * NB + b) * NW + w0;
    bf16x8 v0 = *(const bf16x8*)(row);
    bf16x8 v1 = *(const bf16x8*)(row + 8);
    float val = 0.f;
#pragma unroll
    for (int k = 0; k < 8; ++k) val += vt[k] * tanh_f((float)v0[k] + b2[k]);
#pragma unroll
    for (int k = 0; k < 8; ++k) val += vt[8 + k] * tanh_f((float)v1[k] + b2[8 + k]);
    val += __shfl_xor(val, 1, 64);
    val += __shfl_xor(val, 2, 64);
    val += __shfl_xor(val, 4, 64);
    val += __shfl_xor(val, 8, 64);
    if (wseg == 0) s_u[s] = val;
  }
  __syncthreads();
  float a = s_u[tid], bb2 = s_u[tid + 256];
  float m = fmaxf(a, bb2);
#pragma unroll
  for (int o = 1; o < 64; o <<= 1) m = fmaxf(m, __shfl_xor(m, o, 64));
  if (lane == 0) s_red[wv] = m;
  __syncthreads();
  m = fmaxf(fmaxf(s_red[0], s_red[1]), fmaxf(s_red[2], s_red[3]));
  float e = __expf(a - m) + __expf(bb2 - m);
#pragma unroll
  for (int o = 1; o < 64; o <<= 1) e += __shfl_xor(e, o, 64);
  if (lane == 0) s_red[4 + wv] = e;
  __syncthreads();
  float lz = m + logf(s_red[4] + s_red[5] + s_red[6] + s_red[7]);
  size_t ob = ((size_t)b * NTD + t) * NS;
  out[ob + tid] = a - lz;
  out[ob + tid + 256] = bb2 - lz;
}

extern "C" void kernel_launch(void* const* d_in, const int* in_sizes, int n_in,
                              void* d_out, int out_size, void* d_ws, size_t ws_size,
                              hipStream_t stream) {
  const int*   tokens    = (const int*)d_in[0];
  const float* dec_h0    = (const float*)d_in[1];
  const float* emb_table = (const float*)d_in[2];
  const float* enc_Wih   = (const float*)d_in[3];
  const float* enc_Whh   = (const float*)d_in[4];
  const float* enc_bih   = (const float*)d_in[5];
  const float* enc_bhh   = (const float*)d_in[6];
  // d_in[7] = dec_Wih: unused (decoder input is the zero vector)
  const float* dec_Whh   = (const float*)d_in[8];
  const float* dec_bih   = (const float*)d_in[9];
  const float* dec_bhh   = (const float*)d_in[10];
  const float* W1_w      = (const float*)d_in[11];
  const float* W1_b      = (const float*)d_in[12];
  const float* W2_w      = (const float*)d_in[13];
  const float* W2_b      = (const float*)d_in[14];
  const float* vt_w      = (const float*)d_in[15];
  // d_in[16] = vt_b: constant shift, invariant under log_softmax
  float* out = (float*)d_out;

  char* w = (char*)d_ws;
  size_t off = 0;
  auto alloc = [&](size_t bytes) {
    size_t o = off;
    off += (bytes + 255) & ~(size_t)255;
    return o;
  };
  bf16_t* embfrag = (bf16_t*)(w + alloc((size_t)NS * NB * NE * 2));           // 16.8 MB
  uint32_t* enc_hf = (uint32_t*)(w + alloc((size_t)(NS + 1) * HSTEP_DW * 4)); // 33.6 MB
  uint32_t* dec_hf = (uint32_t*)(w + alloc((size_t)(NTD + 1) * HSTEP_DW * 4)); // 8.5 MB
  bf16_t* blend1  = (bf16_t*)(w + alloc((size_t)NS * NB * NW * 2));           // 16.8 MB
  float*  blend2  = (float*)(w + alloc((size_t)NTD * NB * NW * 4));           // 8.4 MB
  bf16_t* pWih    = (bf16_t*)(w + alloc((size_t)NG * NE * 2));
  bf16_t* pWhhE   = (bf16_t*)(w + alloc((size_t)NG * NH * 2));
  bf16_t* pWhhD   = (bf16_t*)(w + alloc((size_t)NG * NH * 2));
  bf16_t* pW1     = (bf16_t*)(w + alloc((size_t)NW * NH * 2));
  bf16_t* pW2     = (bf16_t*)(w + alloc((size_t)NW * NH * 2));
  uint32_t* flags = (uint32_t*)(w + alloc(512));   // enc 64 | dec 64 dwords
  (void)ws_size; (void)in_sizes; (void)n_in; (void)out_size;

  // per-call init: flags, enc h_0 = 0
  hipMemsetAsync(flags, 0, 512, stream);
  hipMemsetAsync(enc_hf, 0, HSTEP_DW * 4, stream);

  // all weight packing in one launch
  pack_all<<<11264, 256, 0, stream>>>(enc_Wih, pWih, enc_Whh, pWhhE,
                                      dec_Whh, pWhhD, W1_w, pW1, W2_w, pW2);

  // embedding gather + dec h0 pack in one launch
  gather_emb2<<<4160, 256, 0, stream>>>(tokens, emb_table, embfrag, dec_h0, dec_hf);

  // encoder chain (r12 protocol + fused x@Wih.T acc-init; no xih buffer)
  lstm_chain_enc<<<64, 256, 0, stream>>>(pWhhE, pWih, embfrag,
                                         enc_bih, enc_bhh, enc_hf, flags);

  // decoder chain (r12 protocol, standalone); c0 = last encoder h
  lstm_chain_dec<<<64, 256, 0, stream>>>(pWhhD, dec_bih, dec_bhh, dec_hf,
                                         enc_hf + (size_t)NS * HSTEP_DW,
                                         flags + 64);

  // blend1 + blend2 in one launch (LDS-staged coalesced writes)
  gemm_blends<<<dim3(4, 160), 256, 0, stream>>>(
      (const bf16_t*)(enc_hf + HSTEP_DW), pW1, W1_b, blend1,
      (const bf16_t*)(dec_hf + HSTEP_DW), pW2, W2_b, blend2);

  // attention + log_softmax -> out [B,T,S]  (register-hoisted coefficients)
  attn_v2<<<NTD * NB, 256, 0, stream>>>(blend1, blend2, vt_w, out);
}